// Round 16
// baseline (136.112 us; speedup 1.0000x reference)
//
#include <hip/hip_runtime.h>
#include <hip/hip_fp16.h>

#define NN 50000
#define NE 800000

// bucket sort: bucket = dst >> 8 (256 dsts per bucket)
#define NBK 196                    // ceil(50000/256)
#define BSH 8
#define BMASK 255
#define SCAP 5120                  // >= max bucket population (mean 4082, +16 sigma)
#define CHUNK 2048                 // edges per sortA block
#define NBLK_A ((NE + CHUNK - 1) / CHUNK)   // 391
#define NBLK_P ((NN + 63) / 64)             // 782
#define GPAD 4                     // gcur stride = 16 ints = 64 B (1 line per counter)

typedef _Float16 f16x8 __attribute__((ext_vector_type(8)));
typedef float f32x4 __attribute__((ext_vector_type(4)));

__device__ __forceinline__ float h2f_hi(unsigned int u) {
    return __half2float(__ushort_as_half((unsigned short)(u >> 16)));
}

// ---------------- K1: init gcur + convert/transpose weights + folded attn matrices ----------------
// w1t: rows 0-127 = W1 cols (fp16, [n][k]); rows 128-143 = [Wel1 | Wer1] (8+8 cols).
// w2t: rows 0-63 = W2 cols; row 64 = wel2, row 65 = wer2; rows 66-79 = 0.
__global__ __launch_bounds__(256) void init_k(const float* __restrict__ W1,
                                              const float* __restrict__ W2,
                                              const float* __restrict__ al1,
                                              const float* __restrict__ ar1,
                                              const float* __restrict__ al2,
                                              const float* __restrict__ ar2,
                                              __half* __restrict__ w1t,
                                              __half* __restrict__ w2t,
                                              int* __restrict__ gcur) {
    const int i = blockIdx.x * 256 + threadIdx.x;   // 64 blocks = 16384
    {
        const int k = i >> 7, n = i & 127;
        w1t[n * 128 + k] = __float2half(W1[i]);
    }
    if (i < 128 * 64) {
        const int k = i >> 6, n = i & 63;
        w2t[n * 128 + k] = __float2half(W2[i]);
    }
    if (i < 2048) {                 // attn1 tile: j=0..15 (el h / er h-8), k=0..127
        const int j = i >> 7, k = i & 127;
        const int h = j & 7;
        const float* ap = (j < 8) ? al1 : ar1;
        float s = 0.f;
        #pragma unroll
        for (int d = 0; d < 16; d++)
            s += W1[k * 128 + h * 16 + d] * ap[h * 16 + d];
        w1t[(size_t)(128 + j) * 128 + k] = __float2half(s);
    }
    if (i < 256) {                  // attn2: j=0 (el) / 1 (er), k=0..127
        const int j = i >> 7, k = i & 127;
        const float* ap = (j == 0) ? al2 : ar2;
        float s = 0.f;
        #pragma unroll
        for (int d = 0; d < 64; d++)
            s += W2[k * 64 + d] * ap[d];
        w2t[(size_t)(64 + j) * 128 + k] = __float2half(s);
    }
    if (i < 14 * 128) {             // zero pad rows 66-79 of w2t
        w2t[(size_t)(66 + (i >> 7)) * 128 + (i & 127)] = __float2half(0.f);
    }
    if (i < NBK) gcur[i << GPAD] = 0;
}

// ---------------- K2: fused sortA (bucket binning, flat flush) + proj1 (MFMA, folded attn) ----------------
__global__ __launch_bounds__(256) void sortA_proj1_k(const int* __restrict__ src,
                                                     const int* __restrict__ dst,
                                                     const float* __restrict__ wE,
                                                     int* __restrict__ gcur,
                                                     int2* __restrict__ stage,
                                                     const float* __restrict__ x,
                                                     const __half* __restrict__ w1t,
                                                     __half* __restrict__ h1h,
                                                     float* __restrict__ el1,
                                                     float* __restrict__ er1) {
    const int t = threadIdx.x;
    if (blockIdx.x < NBLK_A) {
        // ---- sortA ----
        __shared__ int hcnt[NBK], lexcl[NBK], lcur[NBK], gbase[NBK];
        __shared__ int wsum[4];
        __shared__ int2 lbuf[CHUNK];
        const int e0 = blockIdx.x * CHUNK;
        const int ne = min(CHUNK, NE - e0);
        if (t < NBK) { hcnt[t] = 0; lcur[t] = 0; }
        __syncthreads();
        for (int i = t; i < ne; i += 256) atomicAdd(&hcnt[dst[e0 + i] >> BSH], 1);
        __syncthreads();
        {
            const int lane = t & 63, wid = t >> 6;
            const int v = (t < NBK) ? hcnt[t] : 0;
            int s = v;
            #pragma unroll
            for (int off = 1; off < 64; off <<= 1) {
                int u = __shfl_up(s, off, 64);
                if (lane >= off) s += u;
            }
            if (lane == 63) wsum[wid] = s;
            __syncthreads();
            int add = 0;
            for (int w = 0; w < wid; w++) add += wsum[w];
            if (t < NBK) lexcl[t] = s - v + add;
        }
        __syncthreads();
        if (t < NBK && hcnt[t] > 0) gbase[t] = atomicAdd(&gcur[t << GPAD], hcnt[t]);
        __syncthreads();
        for (int i = t; i < ne; i += 256) {
            const int d = dst[e0 + i];
            const int b = d >> BSH;
            const int r = atomicAdd(&lcur[b], 1);
            lbuf[lexcl[b] + r] = make_int2((src[e0 + i] & 0xFFFF) | ((d & BMASK) << 16) | (b << 24),
                                           __float_as_int(wE[e0 + i]));
        }
        __syncthreads();
        for (int i = t; i < ne; i += 256) {
            const int2 v = lbuf[i];
            const int b = (unsigned int)v.x >> 24;
            const int pos = gbase[b] + (i - lexcl[b]);
            stage[(size_t)b * SCAP + pos] = v;
        }
    } else {
        // ---- proj1 (MFMA): 9 B-tiles, tile 8 = folded [Wel1|Wer1] ----
        const int bid = blockIdx.x - NBLK_A;
        const int l = t & 63, wv = t >> 6;
        const int rbase = bid * 64 + wv * 16;
        const int cl = l & 15, kg = l >> 4;
        const int arow = rbase + cl;
        const float* xrow = x + (size_t)(arow < NN ? arow : NN - 1) * 128;
        f16x8 afrag[4];
        #pragma unroll
        for (int ks = 0; ks < 4; ks++) {
            const float4 u0 = *(const float4*)(xrow + ks * 32 + kg * 8);
            const float4 u1 = *(const float4*)(xrow + ks * 32 + kg * 8 + 4);
            f16x8 a;
            a[0] = (_Float16)u0.x; a[1] = (_Float16)u0.y; a[2] = (_Float16)u0.z; a[3] = (_Float16)u0.w;
            a[4] = (_Float16)u1.x; a[5] = (_Float16)u1.y; a[6] = (_Float16)u1.z; a[7] = (_Float16)u1.w;
            afrag[ks] = a;
        }
        f32x4 acc[9];
        #pragma unroll
        for (int nt = 0; nt < 9; nt++) { acc[nt][0]=0.f; acc[nt][1]=0.f; acc[nt][2]=0.f; acc[nt][3]=0.f; }
        #pragma unroll
        for (int nt = 0; nt < 9; nt++) {
            const f16x8* bp = (const f16x8*)(w1t + (size_t)(nt * 16 + cl) * 128 + kg * 8);
            #pragma unroll
            for (int ks = 0; ks < 4; ks++)
                acc[nt] = __builtin_amdgcn_mfma_f32_16x16x32_f16(afrag[ks], bp[ks * 4], acc[nt], 0, 0, 0);
        }
        const int orow0 = rbase + kg * 4;
        #pragma unroll
        for (int nt = 0; nt < 8; nt++) {
            const int col = nt * 16 + cl;
            #pragma unroll
            for (int r = 0; r < 4; r++) {
                const int orow = orow0 + r;
                if (orow < NN) h1h[(size_t)orow * 128 + col] = __float2half(acc[nt][r]);
            }
        }
        // tile 8: cols 0-7 = el (head cl), cols 8-15 = er (head cl-8)
        #pragma unroll
        for (int r = 0; r < 4; r++) {
            const int orow = orow0 + r;
            if (orow < NN) {
                if (cl < 8) el1[(size_t)orow * 8 + cl] = acc[8][r];
                else        er1[(size_t)orow * 8 + (cl - 8)] = acc[8][r];
            }
        }
    }
}

// ---------------- K3: sortB — per-bucket histogram -> offs, scatter to csr ----------------
__global__ __launch_bounds__(1024) void sortB_k(const int* __restrict__ gcur,
                                                const int2* __restrict__ stage,
                                                int* __restrict__ offs,
                                                unsigned int* __restrict__ csr) {
    __shared__ int cnt[256], cur[256], gall[NBK];
    __shared__ int wsum[4];
    __shared__ int sbase;
    const int b = blockIdx.x, t = threadIdx.x;
    if (t < NBK) gall[t] = gcur[t << GPAD];
    if (t < 256) cnt[t] = 0;
    __syncthreads();
    const int nb = gall[b];
    if (t < 64) {   // wave 0: base = sum gall[0..b)
        int part = 0;
        for (int i = t; i < b; i += 64) part += gall[i];
        #pragma unroll
        for (int m = 1; m < 64; m <<= 1) part += __shfl_xor(part, m, 64);
        if (t == 0) sbase = part;
    }
    const int2* sp = stage + (size_t)b * SCAP;
    for (int i = t; i < nb; i += 1024) atomicAdd(&cnt[(sp[i].x >> 16) & BMASK], 1);
    __syncthreads();
    const int base = sbase;
    const int dlo = b << BSH;
    {   // exclusive scan of cnt[0..256) by threads 0..255
        const int lane = t & 63, wid = t >> 6;
        const int v = (t < 256) ? cnt[t] : 0;
        int s = v;
        #pragma unroll
        for (int off = 1; off < 64; off <<= 1) {
            int u = __shfl_up(s, off, 64);
            if (lane >= off) s += u;
        }
        if (t < 256 && lane == 63) wsum[wid] = s;
        __syncthreads();
        if (t < 256) {
            int add = 0;
            for (int w = 0; w < wid; w++) add += wsum[w];
            const int excl = s - v + add;
            cur[t] = excl;
            if (dlo + t < NN) offs[dlo + t] = base + excl;
        }
        if (b == NBK - 1 && t == 0) offs[NN] = base + nb;
    }
    __syncthreads();
    for (int i = t; i < nb; i += 1024) {
        const int2 pr = sp[i];
        const int dloc = (pr.x >> 16) & BMASK;
        const int sv = pr.x & 0xFFFF;
        const int r = atomicAdd(&cur[dloc], 1);
        const __half hw = __float2half(__int_as_float(pr.y));
        csr[base + r] = (unsigned int)sv | ((unsigned int)__half_as_ushort(hw) << 16);
    }
}

// ---------------- K4: Layer 1 aggregation — TWO nodes per wave, 16-edge tiles ----------------
__global__ __launch_bounds__(128) void agg1_k(const int* __restrict__ offs,
                                              const unsigned int* __restrict__ csr,
                                              const __half* __restrict__ h1h,
                                              const float* __restrict__ el1,
                                              const float* __restrict__ er1,
                                              const float* __restrict__ b1,
                                              __half* __restrict__ h2in_h) {
    const int t = threadIdx.x, w = t >> 6, l = t & 63;
    const int nA = blockIdx.x * 4 + w * 2;
    const int nB = nA + 1;
    const int begA = offs[nA], degA = offs[nA + 1] - begA;
    const int begB = offs[nB], degB = offs[nB + 1] - begB;
    const int h = l & 7, e0 = l >> 3, e1 = e0 + 8;
    const int g = l & 15, es = l >> 4, hg = g >> 1;
    const float erA = er1[(size_t)nA * 8 + h];
    const float erB = er1[(size_t)nB * 8 + h];
    float zA = 0.f, zB = 0.f;
    float accA[8], accB[8];
    #pragma unroll
    for (int j = 0; j < 8; j++) { accA[j] = 0.f; accB[j] = 0.f; }
    const float4* hp4 = (const float4*)h1h;
    const int dmax = max(degA, degB);

    for (int base = 0; base < dmax; base += 16) {
        int pr = 0;
        if (l < 16) { if (base + l < degA) pr = (int)csr[begA + base + l]; }
        else if (l < 32) { const int e = l - 16; if (base + e < degB) pr = (int)csr[begB + base + e]; }
        const unsigned int pA0 = (unsigned int)__shfl(pr, e0, 64);
        const unsigned int pA1 = (unsigned int)__shfl(pr, e1, 64);
        const unsigned int pB0 = (unsigned int)__shfl(pr, 16 + e0, 64);
        const unsigned int pB1 = (unsigned int)__shfl(pr, 16 + e1, 64);
        float lgA0 = -1e30f, lgA1 = -1e30f, lgB0 = -1e30f, lgB1 = -1e30f;
        if (base + e0 < degA) { const float v = el1[(size_t)(pA0 & 0xFFFF) * 8 + h] + erA; lgA0 = v > 0.f ? v : 0.2f * v; }
        if (base + e1 < degA) { const float v = el1[(size_t)(pA1 & 0xFFFF) * 8 + h] + erA; lgA1 = v > 0.f ? v : 0.2f * v; }
        if (base + e0 < degB) { const float v = el1[(size_t)(pB0 & 0xFFFF) * 8 + h] + erB; lgB0 = v > 0.f ? v : 0.2f * v; }
        if (base + e1 < degB) { const float v = el1[(size_t)(pB1 & 0xFFFF) * 8 + h] + erB; lgB1 = v > 0.f ? v : 0.2f * v; }
        const float eA0 = __expf(lgA0), eA1 = __expf(lgA1);
        const float eB0 = __expf(lgB0), eB1 = __expf(lgB1);
        zA += eA0 + eA1;
        zB += eB0 + eB1;
        const float pwA0 = eA0 * h2f_hi(pA0), pwA1 = eA1 * h2f_hi(pA1);
        const float pwB0 = eB0 * h2f_hi(pB0), pwB1 = eB1 * h2f_hi(pB1);
        const int sA0 = __shfl(pr, es, 64) & 0xFFFF;
        const int sA1 = __shfl(pr, es + 4, 64) & 0xFFFF;
        const int sA2 = __shfl(pr, es + 8, 64) & 0xFFFF;
        const int sA3 = __shfl(pr, es + 12, 64) & 0xFFFF;
        const int sB0 = __shfl(pr, 16 + es, 64) & 0xFFFF;
        const int sB1 = __shfl(pr, 16 + es + 4, 64) & 0xFFFF;
        const int sB2 = __shfl(pr, 16 + es + 8, 64) & 0xFFFF;
        const int sB3 = __shfl(pr, 16 + es + 12, 64) & 0xFFFF;
        const float qA0 = __shfl(pwA0, es * 8 + hg, 64);
        const float qA1 = __shfl(pwA0, (es + 4) * 8 + hg, 64);
        const float qA2 = __shfl(pwA1, es * 8 + hg, 64);
        const float qA3 = __shfl(pwA1, (es + 4) * 8 + hg, 64);
        const float qB0 = __shfl(pwB0, es * 8 + hg, 64);
        const float qB1 = __shfl(pwB0, (es + 4) * 8 + hg, 64);
        const float qB2 = __shfl(pwB1, es * 8 + hg, 64);
        const float qB3 = __shfl(pwB1, (es + 4) * 8 + hg, 64);
        const float4 vA0 = hp4[(size_t)sA0 * 16 + g];
        const float4 vA1 = hp4[(size_t)sA1 * 16 + g];
        const float4 vA2 = hp4[(size_t)sA2 * 16 + g];
        const float4 vA3 = hp4[(size_t)sA3 * 16 + g];
        const float4 vB0 = hp4[(size_t)sB0 * 16 + g];
        const float4 vB1 = hp4[(size_t)sB1 * 16 + g];
        const float4 vB2 = hp4[(size_t)sB2 * 16 + g];
        const float4 vB3 = hp4[(size_t)sB3 * 16 + g];
        #pragma unroll
        for (int q = 0; q < 4; q++) {
            const float2 fA0 = __half22float2(((const __half2*)&vA0)[q]);
            const float2 fA1 = __half22float2(((const __half2*)&vA1)[q]);
            const float2 fA2 = __half22float2(((const __half2*)&vA2)[q]);
            const float2 fA3 = __half22float2(((const __half2*)&vA3)[q]);
            accA[2 * q]     = fmaf(qA0, fA0.x, fmaf(qA1, fA1.x, fmaf(qA2, fA2.x, fmaf(qA3, fA3.x, accA[2 * q]))));
            accA[2 * q + 1] = fmaf(qA0, fA0.y, fmaf(qA1, fA1.y, fmaf(qA2, fA2.y, fmaf(qA3, fA3.y, accA[2 * q + 1]))));
            const float2 fB0 = __half22float2(((const __half2*)&vB0)[q]);
            const float2 fB1 = __half22float2(((const __half2*)&vB1)[q]);
            const float2 fB2 = __half22float2(((const __half2*)&vB2)[q]);
            const float2 fB3 = __half22float2(((const __half2*)&vB3)[q]);
            accB[2 * q]     = fmaf(qB0, fB0.x, fmaf(qB1, fB1.x, fmaf(qB2, fB2.x, fmaf(qB3, fB3.x, accB[2 * q]))));
            accB[2 * q + 1] = fmaf(qB0, fB0.y, fmaf(qB1, fB1.y, fmaf(qB2, fB2.y, fmaf(qB3, fB3.y, accB[2 * q + 1]))));
        }
    }
    zA += __shfl_xor(zA, 8, 64);  zA += __shfl_xor(zA, 16, 64);  zA += __shfl_xor(zA, 32, 64);
    zB += __shfl_xor(zB, 8, 64);  zB += __shfl_xor(zB, 16, 64);  zB += __shfl_xor(zB, 32, 64);
    #pragma unroll
    for (int j = 0; j < 8; j++) {
        accA[j] += __shfl_xor(accA[j], 16, 64);
        accA[j] += __shfl_xor(accA[j], 32, 64);
        accB[j] += __shfl_xor(accB[j], 16, 64);
        accB[j] += __shfl_xor(accB[j], 32, 64);
    }
    const float zgA = __shfl(zA, hg, 64);
    const float zgB = __shfl(zB, hg, 64);
    const float4* b4 = (const float4*)b1;
    const float4 bb0 = b4[g * 2], bb1 = b4[g * 2 + 1];
    if (l < 32) {
        const bool isA = (l < 16);
        const int n = isA ? nA : nB;
        const int deg = isA ? degA : degB;
        const float zg = isA ? zgA : zgB;
        const float inv = (deg > 0) ? 1.f / zg : 0.f;
        float ac[8];
        #pragma unroll
        for (int j = 0; j < 8; j++) ac[j] = isA ? accA[j] : accB[j];
        __half hv[8];
        hv[0] = __float2half(fmaxf(ac[0] * inv + bb0.x, 0.f));
        hv[1] = __float2half(fmaxf(ac[1] * inv + bb0.y, 0.f));
        hv[2] = __float2half(fmaxf(ac[2] * inv + bb0.z, 0.f));
        hv[3] = __float2half(fmaxf(ac[3] * inv + bb0.w, 0.f));
        hv[4] = __float2half(fmaxf(ac[4] * inv + bb1.x, 0.f));
        hv[5] = __float2half(fmaxf(ac[5] * inv + bb1.y, 0.f));
        hv[6] = __float2half(fmaxf(ac[6] * inv + bb1.z, 0.f));
        hv[7] = __float2half(fmaxf(ac[7] * inv + bb1.w, 0.f));
        *(int4*)(h2in_h + (size_t)n * 128 + g * 8) = *(const int4*)hv;
    }
}

// ---------------- K5: Layer 2 projection (MFMA, folded attn) ----------------
__global__ __launch_bounds__(256) void proj2_k(const __half* __restrict__ xh,
                                               const __half* __restrict__ w2t,
                                               __half* __restrict__ h2h,
                                               float* __restrict__ el2,
                                               float* __restrict__ er2) {
    const int t = threadIdx.x, l = t & 63, wv = t >> 6;
    const int rbase = blockIdx.x * 64 + wv * 16;
    const int cl = l & 15, kg = l >> 4;
    const int arow = rbase + cl;
    const __half* xrow = xh + (size_t)(arow < NN ? arow : NN - 1) * 128;
    f16x8 afrag[4];
    #pragma unroll
    for (int ks = 0; ks < 4; ks++)
        afrag[ks] = *(const f16x8*)(xrow + ks * 32 + kg * 8);
    f32x4 acc[5];
    #pragma unroll
    for (int nt = 0; nt < 5; nt++) { acc[nt][0]=0.f; acc[nt][1]=0.f; acc[nt][2]=0.f; acc[nt][3]=0.f; }
    #pragma unroll
    for (int nt = 0; nt < 5; nt++) {
        const f16x8* bp = (const f16x8*)(w2t + (size_t)(nt * 16 + cl) * 128 + kg * 8);
        #pragma unroll
        for (int ks = 0; ks < 4; ks++)
            acc[nt] = __builtin_amdgcn_mfma_f32_16x16x32_f16(afrag[ks], bp[ks * 4], acc[nt], 0, 0, 0);
    }
    const int orow0 = rbase + kg * 4;
    #pragma unroll
    for (int nt = 0; nt < 4; nt++) {
        const int col = nt * 16 + cl;
        #pragma unroll
        for (int r = 0; r < 4; r++) {
            const int orow = orow0 + r;
            if (orow < NN) h2h[(size_t)orow * 64 + col] = __float2half(acc[nt][r]);
        }
    }
    // tile 4: col 0 = el2, col 1 = er2
    #pragma unroll
    for (int r = 0; r < 4; r++) {
        const int orow = orow0 + r;
        if (orow < NN) {
            if (cl == 0) el2[orow] = acc[4][r];
            else if (cl == 1) er2[orow] = acc[4][r];
        }
    }
}

// ---------------- K6: Layer 2 aggregation — TWO nodes per wave, 16-edge tiles ----------------
__global__ __launch_bounds__(128) void agg2_k(const int* __restrict__ offs,
                                              const unsigned int* __restrict__ csr,
                                              const __half* __restrict__ h2h,
                                              const float* __restrict__ el2,
                                              const float* __restrict__ er2,
                                              const float* __restrict__ b2,
                                              float* __restrict__ out) {
    const int t = threadIdx.x, w = t >> 6, l = t & 63;
    const int nA = blockIdx.x * 4 + w * 2;
    const int nB = nA + 1;
    const int begA = offs[nA], degA = offs[nA + 1] - begA;
    const int begB = offs[nB], degB = offs[nB + 1] - begB;
    const int g = l & 7, es = l >> 3;
    const float erdA = er2[nA], erdB = er2[nB];
    float zl = 0.f;
    float accA[8], accB[8];
    #pragma unroll
    for (int j = 0; j < 8; j++) { accA[j] = 0.f; accB[j] = 0.f; }
    const float4* hp4 = (const float4*)h2h;
    const int dmax = max(degA, degB);

    for (int base = 0; base < dmax; base += 16) {
        int pr = 0;
        bool okE = false;
        if (l < 16) { okE = (base + l < degA); if (okE) pr = (int)csr[begA + base + l]; }
        else if (l < 32) { const int e = l - 16; okE = (base + e < degB); if (okE) pr = (int)csr[begB + base + e]; }
        float pw = 0.f;
        if (okE) {
            const float er = (l < 16) ? erdA : erdB;
            const float v = el2[(unsigned int)pr & 0xFFFF] + er;
            const float lg = v > 0.f ? v : 0.2f * v;
            const float p = __expf(lg);
            zl += p;
            pw = p * h2f_hi((unsigned int)pr);
        }
        const int sA0 = __shfl(pr, es, 64) & 0xFFFF;
        const int sA1 = __shfl(pr, es + 8, 64) & 0xFFFF;
        const int sB0 = __shfl(pr, 16 + es, 64) & 0xFFFF;
        const int sB1 = __shfl(pr, 16 + es + 8, 64) & 0xFFFF;
        const float qA0 = __shfl(pw, es, 64);
        const float qA1 = __shfl(pw, es + 8, 64);
        const float qB0 = __shfl(pw, 16 + es, 64);
        const float qB1 = __shfl(pw, 16 + es + 8, 64);
        const float4 vA0 = hp4[(size_t)sA0 * 8 + g];
        const float4 vA1 = hp4[(size_t)sA1 * 8 + g];
        const float4 vB0 = hp4[(size_t)sB0 * 8 + g];
        const float4 vB1 = hp4[(size_t)sB1 * 8 + g];
        #pragma unroll
        for (int q = 0; q < 4; q++) {
            const float2 fA0 = __half22float2(((const __half2*)&vA0)[q]);
            const float2 fA1 = __half22float2(((const __half2*)&vA1)[q]);
            accA[2 * q]     = fmaf(qA0, fA0.x, fmaf(qA1, fA1.x, accA[2 * q]));
            accA[2 * q + 1] = fmaf(qA0, fA0.y, fmaf(qA1, fA1.y, accA[2 * q + 1]));
            const float2 fB0 = __half22float2(((const __half2*)&vB0)[q]);
            const float2 fB1 = __half22float2(((const __half2*)&vB1)[q]);
            accB[2 * q]     = fmaf(qB0, fB0.x, fmaf(qB1, fB1.x, accB[2 * q]));
            accB[2 * q + 1] = fmaf(qB0, fB0.y, fmaf(qB1, fB1.y, accB[2 * q + 1]));
        }
    }
    zl += __shfl_xor(zl, 1, 64);
    zl += __shfl_xor(zl, 2, 64);
    zl += __shfl_xor(zl, 4, 64);
    zl += __shfl_xor(zl, 8, 64);
    const float zA = __shfl(zl, 0, 64);
    const float zB = __shfl(zl, 16, 64);
    #pragma unroll
    for (int j = 0; j < 8; j++) {
        accA[j] += __shfl_xor(accA[j], 8, 64);
        accA[j] += __shfl_xor(accA[j], 16, 64);
        accA[j] += __shfl_xor(accA[j], 32, 64);
        accB[j] += __shfl_xor(accB[j], 8, 64);
        accB[j] += __shfl_xor(accB[j], 16, 64);
        accB[j] += __shfl_xor(accB[j], 32, 64);
    }
    const float4* b4 = (const float4*)b2;
    const float4 bb0 = b4[g * 2], bb1 = b4[g * 2 + 1];
    if (l < 8 || (l >= 16 && l < 24)) {
        const bool isA = (l < 8);
        const int n = isA ? nA : nB;
        const int deg = isA ? degA : degB;
        const float z = isA ? zA : zB;
        const float inv = (deg > 0) ? 1.f / z : 0.f;
        float ac[8];
        #pragma unroll
        for (int j = 0; j < 8; j++) ac[j] = isA ? accA[j] : accB[j];
        float4 o0, o1;
        o0.x = ac[0] * inv + bb0.x;
        o0.y = ac[1] * inv + bb0.y;
        o0.z = ac[2] * inv + bb0.z;
        o0.w = ac[3] * inv + bb0.w;
        o1.x = ac[4] * inv + bb1.x;
        o1.y = ac[5] * inv + bb1.y;
        o1.z = ac[6] * inv + bb1.z;
        o1.w = ac[7] * inv + bb1.w;
        float4* op = (float4*)(out + (size_t)n * 64 + g * 8);
        op[0] = o0; op[1] = o1;
    }
}

// ---------------- host ----------------

extern "C" void kernel_launch(void* const* d_in, const int* in_sizes, int n_in,
                              void* d_out, int out_size, void* d_ws, size_t ws_size,
                              hipStream_t stream) {
    const float* feat = (const float*)d_in[0];
    const int*   srcv = (const int*)d_in[1];
    const int*   dstv = (const int*)d_in[2];
    const float* wE   = (const float*)d_in[3];
    const float* W1   = (const float*)d_in[4];
    const float* al1  = (const float*)d_in[5];
    const float* ar1  = (const float*)d_in[6];
    const float* b1   = (const float*)d_in[7];
    const float* W2   = (const float*)d_in[8];
    const float* al2  = (const float*)d_in[9];
    const float* ar2  = (const float*)d_in[10];
    const float* b2   = (const float*)d_in[11];
    float* out = (float*)d_out;

    char* ws = (char*)d_ws;
    size_t off = 0;
    auto take = [&](size_t bytes) -> char* {
        char* pp = ws + off;
        off = (off + bytes + 255) & ~(size_t)255;
        return pp;
    };
    __half* h1h   = (__half*)take((size_t)NN * 128 * 2);
    __half* h2h   = (__half*)take((size_t)NN * 64 * 2);
    __half* h2in_h= (__half*)take((size_t)NN * 128 * 2);   // 12.8 MB; first ~8 MB aliased as sort staging
    float* el1  = (float*)take((size_t)NN * 8 * 4);
    float* er1  = (float*)take((size_t)NN * 8 * 4);
    float* el2  = (float*)take((size_t)NN * 4);
    float* er2  = (float*)take((size_t)NN * 4);
    int* offs   = (int*)take((size_t)(NN + 1) * 4);
    unsigned int* csr = (unsigned int*)take((size_t)NE * 4);
    int* gcur   = (int*)take((size_t)(NBK << GPAD) * 4);
    __half* w1t = (__half*)take((size_t)144 * 128 * 2);    // 128 cols + 16 folded attn cols
    __half* w2t = (__half*)take((size_t)80 * 128 * 2);     // 64 cols + el/er + pad
    int2* stage = (int2*)h2in_h;   // NBK*SCAP*8 = 8.03 MB, consumed (sortB) before agg1 writes h2in_h

    init_k<<<64, 256, 0, stream>>>(W1, W2, al1, ar1, al2, ar2, w1t, w2t, gcur);
    sortA_proj1_k<<<NBLK_A + NBLK_P, 256, 0, stream>>>(srcv, dstv, wE, gcur, stage,
                                                       feat, w1t, h1h, el1, er1);
    sortB_k<<<NBK, 1024, 0, stream>>>(gcur, stage, offs, csr);
    agg1_k<<<NN / 4, 128, 0, stream>>>(offs, csr, h1h, el1, er1, b1, h2in_h);
    proj2_k<<<(NN + 63) / 64, 256, 0, stream>>>(h2in_h, w2t, h2h, el2, er2);
    agg2_k<<<NN / 4, 128, 0, stream>>>(offs, csr, h2h, el2, er2, b2, out);
}